// Round 9
// baseline (138.691 us; speedup 1.0000x reference)
//
#include <hip/hip_runtime.h>

// Sizes (fixed by the problem)
#define B_ 8192
#define T_ 256
#define I_ 28
#define H_ 10

// d_out layout: [B*T*H] output, then [2*B*H] h_final
#define OUT_MAIN (B_ * T_ * H_)   // 20971520
#define BH (B_ * H_)              // 81920

typedef __bf16 bf16x8 __attribute__((ext_vector_type(8)));
typedef float f32x16 __attribute__((ext_vector_type(16)));
typedef float f32x4  __attribute__((ext_vector_type(4)));
union W4u { unsigned int w[4]; bf16x8 v; };

__device__ __forceinline__ float fast_tanh(float x) {
    float e = __builtin_amdgcn_exp2f(x * 2.885390081777927f);
    return __builtin_fmaf(-2.0f, __builtin_amdgcn_rcpf(e + 1.0f), 1.0f);
}

__device__ __forceinline__ unsigned short f2bf(float f) {  // f32 -> bf16 RNE
    unsigned u = __float_as_uint(f);
    unsigned r = ((u >> 16) & 1) + 0x7fff;
    return (unsigned short)((u + r) >> 16);
}

// pack (f0,f1) -> bf16 pair dh, and residual pair dl (split-bf16: f ~= hi + lo)
__device__ __forceinline__ void cvtpair(float f0, float f1, unsigned& dh, unsigned& dl) {
    asm("v_cvt_pk_bf16_f32 %0, %1, %2" : "=v"(dh) : "v"(f0), "v"(f1));
    float r0 = f0 - __uint_as_float(dh << 16);
    float r1 = f1 - __uint_as_float(dh & 0xffff0000u);
    asm("v_cvt_pk_bf16_f32 %0, %1, %2" : "=v"(dl) : "v"(r0), "v"(r1));
}

// C->B rebuild (validated r7): pads land exactly 0
#define REBUILD(vv0,vv1,vv2,vv3,vv4,vv5, DST) { \
    unsigned t01, t23, t45, w3 = 0; \
    asm("v_cvt_pk_bf16_f32 %0, %1, %2" : "=v"(t01) : "v"(vv0), "v"(vv1)); \
    asm("v_cvt_pk_bf16_f32 %0, %1, %2" : "=v"(t23) : "v"(vv2), "v"(vv3)); \
    asm("v_cvt_pk_bf16_f32 %0, %1, %2" : "=v"(t45) : "v"(vv4), "v"(vv5)); \
    asm volatile("s_nop 1" : "+v"(t01), "+v"(t23), "+v"(t45)); \
    asm("v_permlane32_swap_b32 %0, %1" : "+v"(t01), "+v"(t45)); \
    asm("v_permlane32_swap_b32 %0, %1" : "+v"(t23), "+v"(w3)); \
    W4u nb_; nb_.w[0]=t01; nb_.w[1]=t23; nb_.w[2]=t45; nb_.w[3]=w3; \
    DST = nb_.v; }

// r9: x-prefetch as inline-asm loads (non-rematerializable outputs) + counted vmcnt.
// Lane (h=l>>5) coverage per step: SA@x+8h(k 8h..8h+3), SB@x+8h+4, SC@x+16+8h,
// SD@x+20 (h=0: k20..23 real; h=1: harmless dup of 20..23 -- A-frag is 0 for k>=28).
#define GLD4o(dst, addr, OFF) \
    asm volatile("global_load_dwordx4 %0, %1, off offset:" #OFF : "=v"(dst) : "v"(addr));

#define LOADX(SA, SB, SC, SD, tt) { \
    const float* a0_ = xrow + (long)(tt) * I_ + 8 * h; \
    const float* a1_ = xrow + (long)(tt) * I_ + 20; \
    GLD4o(SA, a0_, 0) \
    GLD4o(SB, a0_, 16) \
    GLD4o(SC, a0_, 64) \
    GLD4o(SD, a1_, 0) }

// wait for slot's 4 loads; ties the regs so consuming VALU can't hoist above.
// Safety: exactly 8 asm loads (two younger LOADX) are provably younger at this
// point (volatile mutual order), so vmcnt(8) always completes this slot.
#define WAITX(SA, SB, SC, SD, N) \
    asm volatile("s_waitcnt vmcnt(" #N ")" : "+v"(SA), "+v"(SB), "+v"(SC), "+v"(SD));

// XC = b0 + Wh*xl + Wl*xh + Wh*xh  (split-bf16 -> ~f32-accurate projection)
#define MAKEXC(SA, SB, SC, SD) { \
    W4u xhA, xlA, xhB, xlB; \
    cvtpair(SA[0], SA[1], xhA.w[0], xlA.w[0]); \
    cvtpair(SA[2], SA[3], xhA.w[1], xlA.w[1]); \
    cvtpair(SB[0], SB[1], xhA.w[2], xlA.w[2]); \
    cvtpair(SB[2], SB[3], xhA.w[3], xlA.w[3]); \
    cvtpair(SC[0], SC[1], xhB.w[0], xlB.w[0]); \
    cvtpair(SC[2], SC[3], xhB.w[1], xlB.w[1]); \
    cvtpair(SD[0], SD[1], xhB.w[2], xlB.w[2]); \
    cvtpair(SD[2], SD[3], xhB.w[3], xlB.w[3]); \
    f32x16 xc = __builtin_amdgcn_mfma_f32_32x32x16_bf16(Axh0, xlA.v, C0SEED, 0,0,0); \
    xc = __builtin_amdgcn_mfma_f32_32x32x16_bf16(Axh1, xlB.v, xc, 0,0,0); \
    xc = __builtin_amdgcn_mfma_f32_32x32x16_bf16(Axl0, xhA.v, xc, 0,0,0); \
    xc = __builtin_amdgcn_mfma_f32_32x32x16_bf16(Axl1, xhB.v, xc, 0,0,0); \
    xc = __builtin_amdgcn_mfma_f32_32x32x16_bf16(Axh0, xhA.v, xc, 0,0,0); \
    XC = __builtin_amdgcn_mfma_f32_32x32x16_bf16(Axh1, xhB.v, xc, 0,0,0); }

// one recurrent step. P* = slot to refill (x_{t+4}), N* = slot to consume (x_{t+1})
#define STEP(s8, PA,PB,PC,PD, NA,NB,NC,ND) { \
    int t = tb + (s8); \
    f32x16 c0 = __builtin_amdgcn_mfma_f32_32x32x16_bf16(Ahh0, Bh0, XC, 0,0,0); \
    f32x16 c1 = __builtin_amdgcn_mfma_f32_32x32x16_bf16(Ahh1, Bh1, C1SEED, 0,0,0); \
    v0 = fast_tanh(c0[0]); v1 = fast_tanh(c0[1]); v2 = fast_tanh(c0[2]); \
    v3 = fast_tanh(c0[3]); v4 = fast_tanh(c0[4]); v5 = fast_tanh(c0[5]); \
    REBUILD(v0,v1,v2,v3,v4,v5, Bh0) \
    c1 = __builtin_amdgcn_mfma_f32_32x32x16_bf16(Aih1, Bh0, c1, 0,0,0); \
    g0 = fast_tanh(c1[0]); g1 = fast_tanh(c1[1]); g2 = fast_tanh(c1[2]); \
    g3 = fast_tanh(c1[3]); g4 = fast_tanh(c1[4]); g5 = fast_tanh(c1[5]); \
    float* op = orow + t * H_; \
    *(float4*)(op + xo) = make_float4(g0, g1, g2, g3); \
    if (!h) *(float2*)(op + 8) = make_float2(g4, g5); \
    REBUILD(g0,g1,g2,g3,g4,g5, Bh1) \
    WAITX(NA,NB,NC,ND, 8) \
    MAKEXC(NA,NB,NC,ND) \
    int tl = (t + 4 < T_) ? (t + 4) : (T_ - 1); \
    LOADX(PA,PB,PC,PD, tl) }

__global__ __launch_bounds__(64)
__attribute__((amdgpu_waves_per_eu(1, 1)))
void rnn_fused(const float* __restrict__ x, const float* __restrict__ h0in,
               const float* __restrict__ Wih0, const float* __restrict__ Whh0,
               const float* __restrict__ bih0, const float* __restrict__ bhh0,
               const float* __restrict__ Wih1, const float* __restrict__ Whh1,
               const float* __restrict__ bih1, const float* __restrict__ bhh1,
               float* __restrict__ out, float* __restrict__ hfin) {
    const int l = threadIdx.x;
    const int n = l & 31, h = l >> 5;
    const int bb = blockIdx.x * 32;
    const int am = n;

    // ---- recurrent A-frags (bf16, zero-padded), pinned vs remat (r5 lesson)
    W4u a0u, aiu, ahu;
#pragma unroll
    for (int jj = 0; jj < 4; jj++) {
        int k0 = 8*h + 2*jj, k1 = k0 + 1;
        bool r0 = (am < H_) && (k0 < H_), r1 = (am < H_) && (k1 < H_);
        unsigned lo, hi;
        lo = r0 ? f2bf(Whh0[am*H_+k0]) : 0u; hi = r1 ? f2bf(Whh0[am*H_+k1]) : 0u;
        a0u.w[jj] = lo | (hi<<16);
        lo = r0 ? f2bf(Wih1[am*H_+k0]) : 0u; hi = r1 ? f2bf(Wih1[am*H_+k1]) : 0u;
        aiu.w[jj] = lo | (hi<<16);
        lo = r0 ? f2bf(Whh1[am*H_+k0]) : 0u; hi = r1 ? f2bf(Whh1[am*H_+k1]) : 0u;
        ahu.w[jj] = lo | (hi<<16);
    }
    bf16x8 Ahh0 = a0u.v, Aih1 = aiu.v, Ahh1 = ahu.v;
    asm volatile("" : "+v"(Ahh0), "+v"(Aih1), "+v"(Ahh1));

    // ---- Wih0 split hi/lo A-frags, 2 K-slices (slice s: k = 16s+8h+2jj)
    W4u xh0u, xh1u, xl0u, xl1u;
#pragma unroll
    for (int s = 0; s < 2; s++) {
#pragma unroll
        for (int jj = 0; jj < 4; jj++) {
            int k0 = 16*s + 8*h + 2*jj, k1 = k0 + 1;
            unsigned short h0b=0, h1b=0, l0b=0, l1b=0;
            if (am < H_ && k0 < I_) {
                float f = Wih0[am*I_+k0];
                h0b = f2bf(f);
                l0b = f2bf(f - __uint_as_float(((unsigned)h0b)<<16));
            }
            if (am < H_ && k1 < I_) {
                float f = Wih0[am*I_+k1];
                h1b = f2bf(f);
                l1b = f2bf(f - __uint_as_float(((unsigned)h1b)<<16));
            }
            unsigned wh = (unsigned)h0b | ((unsigned)h1b<<16);
            unsigned wl = (unsigned)l0b | ((unsigned)l1b<<16);
            if (s==0) { xh0u.w[jj]=wh; xl0u.w[jj]=wl; }
            else      { xh1u.w[jj]=wh; xl1u.w[jj]=wl; }
        }
    }
    bf16x8 Axh0 = xh0u.v, Axh1 = xh1u.v, Axl0 = xl0u.v, Axl1 = xl1u.v;
    asm volatile("" : "+v"(Axh0), "+v"(Axh1), "+v"(Axl0), "+v"(Axl1));

    // ---- persistent bias-seeded C tuples, pinned
    f32x16 C0SEED, C1SEED;
#pragma unroll
    for (int r = 0; r < 16; r++) { C0SEED[r] = 0.f; C1SEED[r] = 0.f; }
#pragma unroll
    for (int r = 0; r < 6; r++) {
        int mm = (r & 3) + 8 * (r >> 2) + 4 * h;
        if (mm < H_) {
            C0SEED[r] = bih0[mm] + bhh0[mm];
            C1SEED[r] = bih1[mm] + bhh1[mm];
        }
    }
    asm volatile("" : "+v"(C0SEED), "+v"(C1SEED));

    // ---- initial B fragments from h0 (zero-padded)
    W4u b0u, b1u;
#pragma unroll
    for (int jj = 0; jj < 4; jj++) {
        int k0 = 8*h + 2*jj, k1 = k0 + 1;
        float f0 = (k0 < H_) ? h0in[(bb + n) * H_ + k0] : 0.f;
        float f1 = (k1 < H_) ? h0in[(bb + n) * H_ + k1] : 0.f;
        b0u.w[jj] = (unsigned)f2bf(f0) | ((unsigned)f2bf(f1) << 16);
        f0 = (k0 < H_) ? h0in[BH + (bb + n) * H_ + k0] : 0.f;
        f1 = (k1 < H_) ? h0in[BH + (bb + n) * H_ + k1] : 0.f;
        b1u.w[jj] = (unsigned)f2bf(f0) | ((unsigned)f2bf(f1) << 16);
    }
    bf16x8 Bh0 = b0u.v, Bh1 = b1u.v;

    const float* xrow = x   + (long)(bb + n) * (T_ * I_);
    float*       orow = out + (long)(bb + n) * (T_ * H_);
    const int xo = h ? 4 : 0;

    // ---- 4-deep prefetch ring: 16 named asm-held f32x4 regs
    f32x4 S00, S01, S02, S03, S10, S11, S12, S13;
    f32x4 S20, S21, S22, S23, S30, S31, S32, S33;
    LOADX(S00,S01,S02,S03, 0)
    LOADX(S10,S11,S12,S13, 1)
    LOADX(S20,S21,S22,S23, 2)
    LOADX(S30,S31,S32,S33, 3)

    f32x16 XC;
    WAITX(S00,S01,S02,S03, 12)
    MAKEXC(S00,S01,S02,S03)   // XC for t=0

    float v0,v1,v2,v3,v4,v5, g0,g1,g2,g3,g4,g5;

    for (int it = 0; it < T_ / 8; it++) {
        int tb = it * 8;
        STEP(0, S00,S01,S02,S03, S10,S11,S12,S13)
        STEP(1, S10,S11,S12,S13, S20,S21,S22,S23)
        STEP(2, S20,S21,S22,S23, S30,S31,S32,S33)
        STEP(3, S30,S31,S32,S33, S00,S01,S02,S03)
        STEP(4, S00,S01,S02,S03, S10,S11,S12,S13)
        STEP(5, S10,S11,S12,S13, S20,S21,S22,S23)
        STEP(6, S20,S21,S22,S23, S30,S31,S32,S33)
        STEP(7, S30,S31,S32,S33, S00,S01,S02,S03)
    }
    // ---- h_final
    float* f0p = hfin + (long)(bb + n) * H_;
    *(float4*)(f0p + xo) = make_float4(v0, v1, v2, v3);
    if (!h) *(float2*)(f0p + 8) = make_float2(v4, v5);
    float* f1p = f0p + BH;
    *(float4*)(f1p + xo) = make_float4(g0, g1, g2, g3);
    if (!h) *(float2*)(f1p + 8) = make_float2(g4, g5);
}

extern "C" void kernel_launch(void* const* d_in, const int* in_sizes, int n_in,
                              void* d_out, int out_size, void* d_ws, size_t ws_size,
                              hipStream_t stream) {
    const float* x     = (const float*)d_in[0];
    const float* h0in  = (const float*)d_in[1];
    const float* Wih0  = (const float*)d_in[2];
    const float* Whh0  = (const float*)d_in[3];
    const float* bih0  = (const float*)d_in[4];
    const float* bhh0  = (const float*)d_in[5];
    const float* Wih1  = (const float*)d_in[6];
    const float* Whh1  = (const float*)d_in[7];
    const float* bih1  = (const float*)d_in[8];
    const float* bhh1  = (const float*)d_in[9];
    float* out = (float*)d_out;

    rnn_fused<<<dim3(B_ / 32), dim3(64), 0, stream>>>(
        x, h0in, Wih0, Whh0, bih0, bhh0, Wih1, Whh1, bih1, bhh1,
        out, out + OUT_MAIN);
}